// Round 6
// baseline (23377.116 us; speedup 1.0000x reference)
//
#include <hip/hip_runtime.h>
#include <math.h>

// HybridQLSTM persistent kernel v9: v6 base (proven 12.6 ms) minus the h
// round. 2 barrier rounds/step (hid, gates). After the gates round every
// block redundantly computes the cell update for exactly the 64 h-elements
// each lane consumes as next-step stage1 A-fragments (row brow, cols
// 32*kt+8*quad+j) -> h lives only in registers, no h store/load/round.
// Replicated c is bit-identical across blocks (same u16 gate bits, same
// FP ops). Plus 240 heater blocks (pure FMA spin, separate-line done-flag
// poll) to hold DPM clocks up while workers are latency-bound.
// T=1024, B=64, D_IN=256, H=256. Grid 256: bid<16 = workers (fixed roles,
// no election), bid>=16 = heaters.

#define TS    1024
#define NELEM 16384

typedef unsigned long long u64;
typedef unsigned int u32;
typedef unsigned short u16;
typedef _Float16 f16;
typedef __attribute__((ext_vector_type(8))) _Float16 half8;
typedef __attribute__((ext_vector_type(8))) unsigned short ushort8;
typedef __attribute__((ext_vector_type(4))) float f32x4;

// ---- relaxed agent-scope (IC-coherent) accessors ----
__device__ __forceinline__ u64 ld_a8(const u64* p) {
    return __hip_atomic_load(p, __ATOMIC_RELAXED, __HIP_MEMORY_SCOPE_AGENT);
}
__device__ __forceinline__ void st_a8(u64* p, u64 v) {
    __hip_atomic_store(p, v, __ATOMIC_RELAXED, __HIP_MEMORY_SCOPE_AGENT);
}
__device__ __forceinline__ int ld_a4(const int* p) {
    return __hip_atomic_load(p, __ATOMIC_RELAXED, __HIP_MEMORY_SCOPE_AGENT);
}
__device__ __forceinline__ void st_a4(int* p, int v) {
    __hip_atomic_store(p, v, __ATOMIC_RELAXED, __HIP_MEMORY_SCOPE_AGENT);
}

// fast tanh/sigmoid via v_exp/v_rcp (err ~1e-6, << 16-bit quantization)
__device__ __forceinline__ float fast_tanh(float xx) {
    float e = __expf(2.0f * xx);
    return 1.0f - 2.0f * __builtin_amdgcn_rcpf(e + 1.0f);
}
__device__ __forceinline__ float fast_sig(float xx) {
    return __builtin_amdgcn_rcpf(1.0f + __expf(-xx));
}

// ---- barrier over 16 worker blocks (v6 mechanism, proven) ----
__device__ __forceinline__ void gbar(int e, int bid, int tid, int* flags) {
    __syncthreads();
    if (tid == 0) st_a4(&flags[bid], e);
    if (tid < 64) {
        for (;;) {
            int ok = 1;
            if (tid < 16) ok = (ld_a4(&flags[tid]) >= e);
            if (__all(ok)) break;
            __builtin_amdgcn_s_sleep(1);
        }
    }
    __syncthreads();
    asm volatile("" ::: "memory");
}

__device__ __forceinline__ half8 h8_from(u64 v0, u64 v1) {
    ushort8 t;
#pragma unroll
    for (int q = 0; q < 4; ++q) {
        t[q]     = (u16)(v0 >> (16 * q));
        t[4 + q] = (u16)(v1 >> (16 * q));
    }
    return __builtin_bit_cast(half8, t);
}

// 4x4 transpose across 4 consecutive lanes (p = lane&3).
__device__ __forceinline__ void xpose4(float v[4], int p) {
#pragma unroll
    for (int m = 1; m <= 2; m <<= 1) {
        float nv[4];
#pragma unroll
        for (int r = 0; r < 4; ++r) {
            float ex = __shfl_xor(v[r ^ m], m);
            nv[r] = ((r ^ p) & m) ? ex : v[r];
        }
#pragma unroll
        for (int r = 0; r < 4; ++r) v[r] = nv[r];
    }
}
__device__ __forceinline__ u64 pk4f16(const float v[4]) {
    u64 r = 0;
#pragma unroll
    for (int k = 0; k < 4; ++k)
        r |= (u64)__builtin_bit_cast(u16, (f16)v[k]) << (16 * k);
    return r;
}
__device__ __forceinline__ u64 pk4q16(const float v[4]) {
    u64 r = 0;
#pragma unroll
    for (int k = 0; k < 4; ++k)
        r |= (u64)(u16)(v[k] * 65535.0f + 0.5f) << (16 * k);
    return r;
}

// ---- init: zero flags + done word; reruns every launch/replay ----
__global__ __launch_bounds__(64) void qinit(int* flags) {
    int i = threadIdx.x;
    if (i < 16) st_a4(&flags[i], 0);
    if (i == 16) st_a4(&flags[32], 0);   // done word, separate 64B line
}

// ---- persistent kernel: 16 workers + 240 clock-heaters ----
__global__ __launch_bounds__(256, 1) void qlstm_persist(
    const float* __restrict__ x,      // [TS, 64, 256] fp32
    const float* __restrict__ W1,     // [4, 512, 256]
    const float* __restrict__ b1,     // [4, 256]
    const float* __restrict__ W2,     // [4, 256, 256]
    const float* __restrict__ b2,     // [4, 256]
    float* __restrict__ out,          // stacked ++ hx ++ cx
    u64* __restrict__ hid64,          // [4][64][64] hid f16, u64-packed
    u64* __restrict__ gat64,          // [4][64][64] gates u16-fixed, packed
    int* __restrict__ flags)          // [0..15] barrier, [32] done
{
    const int tid = threadIdx.x;
    const int bid = blockIdx.x;

    // ---- heater path: pure-VALU spin to hold DPM clocks up ----
    if (bid >= 16) {
        float r0 = 0.5f + tid, r1 = 1.5f + tid, r2 = 2.5f, r3 = 3.5f;
        for (;;) {
#pragma unroll 16
            for (int it = 0; it < 512; ++it) {
                r0 = __builtin_fmaf(r0, 0.9999999f, 1.0f);
                r1 = __builtin_fmaf(r1, 0.9999999f, 1.0f);
                r2 = __builtin_fmaf(r2, 0.9999999f, 1.0f);
                r3 = __builtin_fmaf(r3, 0.9999999f, 1.0f);
            }
            asm volatile("" :: "v"(r0), "v"(r1), "v"(r2), "v"(r3));
            if (ld_a4(&flags[32]) != 0) break;
        }
        return;
    }

    const int g  = bid >> 2;          // gate 0..3
    const int ct = bid & 3;           // column tile 0..3 (64 cols)

    // LDS: W1 [16 kt][4 nt][64 lanes][8 f16] = 64 KB ; W2 [8 kt][4 nt][...] = 32 KB
    __shared__ f16 w1s[16 * 4 * 512];
    __shared__ f16 w2s[8 * 4 * 512];
    {
        const float* W1g = W1 + (size_t)g * 512 * 256;
        for (int i = tid; i < 16 * 4 * 64; i += 256) {
            int kt = i >> 8, nt = (i >> 6) & 3, lane = i & 63;
            int k0 = kt * 32 + (lane >> 4) * 8;
            int col = ct * 64 + nt * 16 + (lane & 15);
#pragma unroll
            for (int j = 0; j < 8; ++j)
                w1s[(size_t)i * 8 + j] = (f16)W1g[(size_t)(k0 + j) * 256 + col];
        }
        const float* W2g = W2 + (size_t)g * 256 * 256;
        for (int i = tid; i < 8 * 4 * 64; i += 256) {
            int kt = i >> 8, nt = (i >> 6) & 3, lane = i & 63;
            int k0 = kt * 32 + (lane >> 4) * 8;
            int col = ct * 64 + nt * 16 + (lane & 15);
#pragma unroll
            for (int j = 0; j < 8; ++j)
                w2s[(size_t)i * 8 + j] = (f16)W2g[(size_t)(k0 + j) * 256 + col];
        }
        __syncthreads();
    }

    const int l    = tid & 63;
    const int w    = tid >> 6;        // wave: A-rows w*16 .. w*16+15
    const int quad = l >> 4;
    const int n15  = l & 15;
    const int brow = w * 16 + n15;    // A-operand row this lane loads/updates
    const int bo   = w * 16 + quad * 4;  // C/D row base
    const int p    = l & 3;           // lane-in-quad for 4x4 transposes
    const int cqb  = ct * 16 + (n15 >> 2);  // packed u64-col base (+ nt*4)
    float b1v[4], b2v[4];
#pragma unroll
    for (int nt = 0; nt < 4; ++nt) {
        b1v[nt] = b1[g * 256 + ct * 64 + nt * 16 + n15];
        b2v[nt] = b2[g * 256 + ct * 64 + nt * 16 + n15];
    }

    // private replica of c for (row brow, cols 32*kt+8*quad+j), k=kt*8+j
    float creg[64];
#pragma unroll
    for (int k = 0; k < 64; ++k) creg[k] = 0.f;
    // h A-fragments (valid from t>=1)
    half8 hfr[8];
#pragma unroll
    for (int kt = 0; kt < 8; ++kt) hfr[kt] = (half8)(f16)0.f;

    f32x4 acc[4];
#pragma unroll
    for (int nt = 0; nt < 4; ++nt) acc[nt] = (f32x4){0.f, 0.f, 0.f, 0.f};

    // ---- stage1 x-part (kt 0..7), peeled for t=0 (h(0)=0 -> no h-part) ----
    {
        const float* xr = x + (size_t)brow * 256;
#pragma unroll
        for (int kt = 0; kt < 8; ++kt) {
            float a[8];
            *(float4*)&a[0] = *(const float4*)(xr + kt * 32 + quad * 8);
            *(float4*)&a[4] = *(const float4*)(xr + kt * 32 + quad * 8 + 4);
            half8 ah;
#pragma unroll
            for (int j = 0; j < 8; ++j) ah[j] = (f16)a[j];
#pragma unroll
            for (int nt = 0; nt < 4; ++nt)
                acc[nt] = __builtin_amdgcn_mfma_f32_16x16x32_f16(
                    ah, *(const half8*)&w1s[((kt * 4 + nt) * 64 + l) * 8], acc[nt], 0, 0, 0);
        }
    }

    for (int t = 0; t < TS; ++t) {
        // ---- stage1 h-part (kt 8..15): A = in-register h fragments ----
        if (t > 0) {
#pragma unroll
            for (int kt = 0; kt < 8; ++kt)
#pragma unroll
                for (int nt = 0; nt < 4; ++nt)
                    acc[nt] = __builtin_amdgcn_mfma_f32_16x16x32_f16(
                        hfr[kt], *(const half8*)&w1s[(((kt + 8) * 4 + nt) * 64 + l) * 8],
                        acc[nt], 0, 0, 0);
        }

        // ---- hid = tanh(acc + b1): transpose, 1 packed u64 store per nt ----
#pragma unroll
        for (int nt = 0; nt < 4; ++nt) {
            float mv[4];
#pragma unroll
            for (int r = 0; r < 4; ++r) mv[r] = fast_tanh(acc[nt][r] + b1v[nt]);
            xpose4(mv, p);   // lane now holds row bo+p, 4 consecutive cols
            st_a8(&hid64[(size_t)(g * 64 + bo + p) * 64 + cqb + nt * 4], pk4f16(mv));
        }

        gbar(2 * t + 1, bid, tid, flags);       // hid(t) visible

        // ---- stage2: gates = sigmoid(hid @ W2 + b2) -> packed u16 fixed ----
        {
            f32x4 s2[4];
#pragma unroll
            for (int nt = 0; nt < 4; ++nt) s2[nt] = (f32x4){0.f, 0.f, 0.f, 0.f};
            const u64* hr = hid64 + (size_t)(g * 64 + brow) * 64;
            u64 mv2[16];
#pragma unroll
            for (int kt = 0; kt < 8; ++kt) {
                int ko = kt * 8 + quad * 2;
                mv2[kt * 2]     = ld_a8(hr + ko);
                mv2[kt * 2 + 1] = ld_a8(hr + ko + 1);
            }
#pragma unroll
            for (int kt = 0; kt < 8; ++kt) {
                half8 ah = h8_from(mv2[kt * 2], mv2[kt * 2 + 1]);
#pragma unroll
                for (int nt = 0; nt < 4; ++nt)
                    s2[nt] = __builtin_amdgcn_mfma_f32_16x16x32_f16(
                        ah, *(const half8*)&w2s[((kt * 4 + nt) * 64 + l) * 8], s2[nt], 0, 0, 0);
            }
#pragma unroll
            for (int nt = 0; nt < 4; ++nt) {
                float gv[4];
#pragma unroll
                for (int r = 0; r < 4; ++r) {
                    float sg = fast_sig(s2[nt][r] + b2v[nt]);
                    if (g == 2) sg = fast_tanh(sg);   // u-gate: pre-apply tanh
                    gv[r] = sg;
                }
                xpose4(gv, p);
                st_a8(&gat64[(size_t)(g * 64 + bo + p) * 64 + cqb + nt * 4], pk4q16(gv));
            }
        }

        gbar(2 * t + 2, bid, tid, flags);       // gates(t) visible

        // ---- issue gate loads for this lane's 64 elements (4 g x 16 u64) ----
        u64 qv[4][16];
#pragma unroll
        for (int gg = 0; gg < 4; ++gg) {
            const u64* gp = gat64 + (size_t)(gg * 64 + brow) * 64 + quad * 2;
#pragma unroll
            for (int kt = 0; kt < 8; ++kt) {
                qv[gg][kt * 2]     = ld_a8(gp + kt * 8);
                qv[gg][kt * 2 + 1] = ld_a8(gp + kt * 8 + 1);
            }
        }

        // ---- stage1 x-part for t+1 (overlaps gate-load latency) ----
#pragma unroll
        for (int nt = 0; nt < 4; ++nt) acc[nt] = (f32x4){0.f, 0.f, 0.f, 0.f};
        if (t < TS - 1) {
            const float* xr = x + ((size_t)(t + 1) * 64 + brow) * 256;
#pragma unroll
            for (int kt = 0; kt < 8; ++kt) {
                float a[8];
                *(float4*)&a[0] = *(const float4*)(xr + kt * 32 + quad * 8);
                *(float4*)&a[4] = *(const float4*)(xr + kt * 32 + quad * 8 + 4);
                half8 ah;
#pragma unroll
                for (int j = 0; j < 8; ++j) ah[j] = (f16)a[j];
#pragma unroll
                for (int nt = 0; nt < 4; ++nt)
                    acc[nt] = __builtin_amdgcn_mfma_f32_16x16x32_f16(
                        ah, *(const half8*)&w1s[((kt * 4 + nt) * 64 + l) * 8], acc[nt], 0, 0, 0);
            }
        }

        // ---- redundant update: c/h for exactly this lane's A-frag elements ----
        {
            const float s = 1.0f / 65535.0f;
#pragma unroll
            for (int kt = 0; kt < 8; ++kt) {
                float hv8[8];
#pragma unroll
                for (int j = 0; j < 8; ++j) {
                    int b = j >> 2, sh = 16 * (j & 3);
                    float f  = (float)((qv[0][kt * 2 + b] >> sh) & 0xffff) * s;
                    float ig = (float)((qv[1][kt * 2 + b] >> sh) & 0xffff) * s;
                    float ug = (float)((qv[2][kt * 2 + b] >> sh) & 0xffff) * s;  // tanh pre-applied
                    float og = (float)((qv[3][kt * 2 + b] >> sh) & 0xffff) * s;
                    float cn = f * creg[kt * 8 + j] + ig * ug;
                    creg[kt * 8 + j] = cn;
                    hv8[j] = og * fast_tanh(cn);
                }
                half8 hh;
#pragma unroll
                for (int j = 0; j < 8; ++j) hh[j] = (f16)hv8[j];
                hfr[kt] = hh;
                // unique writer: wave g, kt within this block's column tile
                if (w == g && (kt >> 1) == ct) {
                    float* op = out + (size_t)t * NELEM + (size_t)brow * 256 + kt * 32 + quad * 8;
                    *(float4*)op       = (float4){hv8[0], hv8[1], hv8[2], hv8[3]};
                    *(float4*)(op + 4) = (float4){hv8[4], hv8[5], hv8[6], hv8[7]};
                    if (t == TS - 1) {
                        float* hp = out + (size_t)TS * NELEM + (size_t)brow * 256 + kt * 32 + quad * 8;
                        *(float4*)hp       = (float4){hv8[0], hv8[1], hv8[2], hv8[3]};
                        *(float4*)(hp + 4) = (float4){hv8[4], hv8[5], hv8[6], hv8[7]};
                        float* cp = hp + NELEM;
                        *(float4*)cp       = (float4){creg[kt*8+0], creg[kt*8+1], creg[kt*8+2], creg[kt*8+3]};
                        *(float4*)(cp + 4) = (float4){creg[kt*8+4], creg[kt*8+5], creg[kt*8+6], creg[kt*8+7]};
                    }
                }
            }
        }
    }

    // release heaters
    if (bid == 0 && tid == 0) st_a4(&flags[32], 1);
}

extern "C" void kernel_launch(void* const* d_in, const int* in_sizes, int n_in,
                              void* d_out, int out_size, void* d_ws, size_t ws_size,
                              hipStream_t stream)
{
    const float* x  = (const float*)d_in[0];
    const float* W1 = (const float*)d_in[1];
    const float* b1 = (const float*)d_in[2];
    const float* W2 = (const float*)d_in[3];
    const float* b2 = (const float*)d_in[4];
    float* out = (float*)d_out;

    char* ws = (char*)d_ws;
    u64* hid64 = (u64*)ws;                      // 128 KB: [4][64][64] u64
    u64* gat64 = (u64*)(ws + 131072);           // 128 KB: [4][64][64] u64
    int* flags = (int*)(ws + 131072 + 131072);  // 256 B: barrier + done

    qinit<<<1, 64, 0, stream>>>(flags);
    qlstm_persist<<<256, 256, 0, stream>>>(x, W1, b1, W2, b2, out,
                                           hid64, gat64, flags);
}